// Round 1
// baseline (544.962 us; speedup 1.0000x reference)
//
#include <hip/hip_runtime.h>

// RNN: h_t = tanh(x_t * W_ih^T + b_ih + h_{t-1} W_hh^T + b_hh), out = h_T W_fc^T + b_fc
// B=8192, T=784, I=1, H=30 (padded to 32), C=10. All fp32.
//
// Parallelization: 8 threads per batch element, each owns ROWS=4 rows of W_hh
// (held fully in VGPRs, ~128 regs). h[32] per batch lives in LDS, double
// buffered, row stride 36 floats (16B aligned; 8 batches/wave hit distinct
// bank quads -> conflict-free ds_read_b128). One __syncthreads per time step.

#define BB 8192
#define TT 784
#define HH 30
#define HP 32      // padded H
#define CC 10
#define NB 32      // batches per workgroup
#define TPB 8      // threads per batch
#define ROWS 4     // rows of W_hh per thread
#define LSTR 36    // LDS row stride in floats (16B-aligned, conflict-free)

__global__ __launch_bounds__(256, 1)
void rnn_scan_kernel(const float* __restrict__ x,
                     const float* __restrict__ W_ih,
                     const float* __restrict__ W_hh,
                     const float* __restrict__ b_ih,
                     const float* __restrict__ b_hh,
                     const float* __restrict__ W_fc,
                     const float* __restrict__ b_fc,
                     float* __restrict__ out) {
    __shared__ float hbuf[2][NB * LSTR];

    const int tid = threadIdx.x;
    const int bl  = tid >> 3;          // local batch index 0..31
    const int r   = tid & 7;           // row-group index 0..7
    const int i0  = r * ROWS;          // first owned row (0,4,...,28)
    const int b   = blockIdx.x * NB + bl;

    // --- Load this thread's 4 rows of W_hh into registers (zero-padded) ---
    float w[ROWS][HP];
    float bias[ROWS], wih[ROWS];
#pragma unroll
    for (int rr = 0; rr < ROWS; ++rr) {
        const int i = i0 + rr;
        const bool valid = (i < HH);
#pragma unroll
        for (int j = 0; j < HP; ++j)
            w[rr][j] = (valid && (j < HH)) ? W_hh[i * HH + j] : 0.0f;
        bias[rr] = valid ? (b_ih[i] + b_hh[i]) : 0.0f;
        wih[rr]  = valid ? W_ih[i] : 0.0f;
    }

    // --- h0 = 0 ---
    const float4 z4 = make_float4(0.f, 0.f, 0.f, 0.f);
    *(float4*)&hbuf[0][bl * LSTR + i0] = z4;
    __syncthreads();

    const float* xb = x + (size_t)b * TT;
    float4 xq = *(const float4*)(xb);   // x[b][0..3]

    int cur = 0;
    for (int q = 0; q < TT / 4; ++q) {
        // prefetch next x quad while we chew through 4 barriered steps
        float4 nxt = (q + 1 < TT / 4) ? *(const float4*)(xb + (q + 1) * 4) : z4;
#pragma unroll
        for (int u = 0; u < 4; ++u) {
            const float xt = (u == 0) ? xq.x : (u == 1) ? xq.y
                           : (u == 2) ? xq.z : xq.w;
            const float* hp = &hbuf[cur][bl * LSTR];
            float acc[ROWS];
#pragma unroll
            for (int rr = 0; rr < ROWS; ++rr)
                acc[rr] = bias[rr] + xt * wih[rr];
#pragma unroll
            for (int jq = 0; jq < HP / 4; ++jq) {
                const float4 hq = *(const float4*)(hp + jq * 4);
#pragma unroll
                for (int rr = 0; rr < ROWS; ++rr) {
                    acc[rr] += w[rr][jq * 4 + 0] * hq.x;
                    acc[rr] += w[rr][jq * 4 + 1] * hq.y;
                    acc[rr] += w[rr][jq * 4 + 2] * hq.z;
                    acc[rr] += w[rr][jq * 4 + 3] * hq.w;
                }
            }
            // tanh(a) = 1 - 2/(e^{2a}+1)  (exact form; v_exp + v_rcp)
            float4 hn;
            float* hnp = (float*)&hn;
#pragma unroll
            for (int rr = 0; rr < ROWS; ++rr) {
                const float e = __expf(2.0f * acc[rr]);
                hnp[rr] = 1.0f - 2.0f * __builtin_amdgcn_rcpf(e + 1.0f);
            }
            *(float4*)&hbuf[cur ^ 1][bl * LSTR + i0] = hn;
            cur ^= 1;
            __syncthreads();
        }
        xq = nxt;
    }

    // --- FC head: out[b][c] = W_fc[c,:] . h_T + b_fc[c] ---
    // After 784 toggles cur is back to 0.
    const float* hf = &hbuf[0][bl * LSTR];
    for (int c = r; c < CC; c += TPB) {
        float acc = b_fc[c];
#pragma unroll
        for (int j = 0; j < HH; ++j)
            acc += W_fc[c * HH + j] * hf[j];
        out[(size_t)b * CC + c] = acc;
    }
}

extern "C" void kernel_launch(void* const* d_in, const int* in_sizes, int n_in,
                              void* d_out, int out_size, void* d_ws, size_t ws_size,
                              hipStream_t stream) {
    const float* x    = (const float*)d_in[0];
    const float* W_ih = (const float*)d_in[1];
    const float* W_hh = (const float*)d_in[2];
    const float* b_ih = (const float*)d_in[3];
    const float* b_hh = (const float*)d_in[4];
    const float* W_fc = (const float*)d_in[5];
    const float* b_fc = (const float*)d_in[6];

    hipLaunchKernelGGL(rnn_scan_kernel,
                       dim3(BB / NB), dim3(NB * TPB), 0, stream,
                       x, W_ih, W_hh, b_ih, b_hh, W_fc, b_fc,
                       (float*)d_out);
}

// Round 2
// 291.294 us; speedup vs baseline: 1.8708x; 1.8708x over previous
//
#include <hip/hip_runtime.h>

// RNN: h_t = tanh(x_t * W_ih^T + b_ih + h_{t-1} W_hh^T + b_hh), out = h_T W_fc^T + b_fc
// B=8192, T=784, I=1, H=30 (pad 32), C=10. fp32.
//
// R2 design: 16 threads per batch, each owns ROWS=2 rows of W_hh in VGPRs
// (64 floats — small enough that the allocator keeps them resident; R1's
// ROWS=4/128-float version came back VGPR_Count=84 => rematerialized loads).
// The 16 threads of a batch live in ONE wave (lanes 16k..16k+15), so the
// h exchange through LDS needs NO __syncthreads: wave lockstep + in-order
// DS pipe order write(t) before read(t+1). 2048 waves total = 2/SIMD.

#define BB 8192
#define TT 784
#define HH 30
#define HP 32
#define CC 10
#define TPB 16     // threads per batch
#define ROWS 2     // rows of W_hh per thread
#define NB 16      // batches per 256-thread block (4 per wave)
#define LSTR 36    // LDS row stride (floats)

__global__ __launch_bounds__(256, 2)
void rnn_scan_kernel(const float* __restrict__ x,
                     const float* __restrict__ W_ih,
                     const float* __restrict__ W_hh,
                     const float* __restrict__ b_ih,
                     const float* __restrict__ b_hh,
                     const float* __restrict__ W_fc,
                     const float* __restrict__ b_fc,
                     float* __restrict__ out) {
    __shared__ float hbuf[NB * LSTR];

    const int tid = threadIdx.x;
    const int bl  = tid >> 4;          // local batch 0..15 (wave-local: 4/wave)
    const int r   = tid & 15;          // row-group 0..15
    const int i0  = r * ROWS;          // owned rows i0, i0+1
    const int b   = blockIdx.x * NB + bl;

    // --- per-thread weights: 2 rows x 32 cols, zero-padded ---
    float w[ROWS][HP];
    float bias[ROWS], wih[ROWS];
#pragma unroll
    for (int rr = 0; rr < ROWS; ++rr) {
        const int i = i0 + rr;
        const bool valid = (i < HH);
#pragma unroll
        for (int j = 0; j < HP; ++j)
            w[rr][j] = (valid && (j < HH)) ? W_hh[i * HH + j] : 0.0f;
        bias[rr] = valid ? (b_ih[i] + b_hh[i]) : 0.0f;
        wih[rr]  = valid ? W_ih[i] : 0.0f;
    }

    float* hp = &hbuf[bl * LSTR];
    // h0 = 0 (each thread zeroes its own 2 slots; wave-local, no barrier)
    *(float2*)&hp[i0] = make_float2(0.f, 0.f);
    __builtin_amdgcn_wave_barrier();

    const float* xb = x + (size_t)b * TT;
    float4 xq = *(const float4*)(xb);

    for (int q = 0; q < TT / 4; ++q) {
        float4 nxt = (q + 1 < TT / 4) ? *(const float4*)(xb + (q + 1) * 4)
                                      : make_float4(0.f, 0.f, 0.f, 0.f);
#pragma unroll
        for (int u = 0; u < 4; ++u) {
            const float xt = (u == 0) ? xq.x : (u == 1) ? xq.y
                           : (u == 2) ? xq.z : xq.w;
            // two partial sums per row -> 4 independent FMA chains
            float a0 = bias[0] + xt * wih[0], a0b = 0.f;
            float a1 = bias[1] + xt * wih[1], a1b = 0.f;
#pragma unroll
            for (int jq = 0; jq < HP / 4; ++jq) {
                const float4 hq = *(const float4*)(hp + jq * 4);
                a0  += w[0][jq * 4 + 0] * hq.x;
                a0b += w[0][jq * 4 + 1] * hq.y;
                a0  += w[0][jq * 4 + 2] * hq.z;
                a0b += w[0][jq * 4 + 3] * hq.w;
                a1  += w[1][jq * 4 + 0] * hq.x;
                a1b += w[1][jq * 4 + 1] * hq.y;
                a1  += w[1][jq * 4 + 2] * hq.z;
                a1b += w[1][jq * 4 + 3] * hq.w;
            }
            const float acc0 = a0 + a0b;
            const float acc1 = a1 + a1b;
            // tanh(a) = 1 - 2/(e^{2a}+1)
            float2 hn;
            hn.x = 1.0f - 2.0f * __builtin_amdgcn_rcpf(__expf(2.0f * acc0) + 1.0f);
            hn.y = 1.0f - 2.0f * __builtin_amdgcn_rcpf(__expf(2.0f * acc1) + 1.0f);
            __builtin_amdgcn_wave_barrier();   // keep reads(t) before write(t)
            *(float2*)&hp[i0] = hn;
            __builtin_amdgcn_wave_barrier();   // keep write(t) before reads(t+1)
        }
        xq = nxt;
    }

    // --- FC head: wave-local h is final; threads r<10 each do one output ---
    if (r < CC) {
        const int c = r;
        float acc = b_fc[c];
#pragma unroll
        for (int j = 0; j < HH; ++j)
            acc += W_fc[c * HH + j] * hp[j];
        out[(size_t)b * CC + c] = acc;
    }
}

extern "C" void kernel_launch(void* const* d_in, const int* in_sizes, int n_in,
                              void* d_out, int out_size, void* d_ws, size_t ws_size,
                              hipStream_t stream) {
    const float* x    = (const float*)d_in[0];
    const float* W_ih = (const float*)d_in[1];
    const float* W_hh = (const float*)d_in[2];
    const float* b_ih = (const float*)d_in[3];
    const float* b_hh = (const float*)d_in[4];
    const float* W_fc = (const float*)d_in[5];
    const float* b_fc = (const float*)d_in[6];

    hipLaunchKernelGGL(rnn_scan_kernel,
                       dim3(BB / NB), dim3(NB * TPB), 0, stream,
                       x, W_ih, W_hh, b_ih, b_hh, W_fc, b_fc,
                       (float*)d_out);
}